// Round 17
// baseline (132.715 us; speedup 1.0000x reference)
//
#include <hip/hip_runtime.h>
#include <stdint.h>

#define IN_F 2048
#define OUT_F 2048
#define BM 128
#define BN 256
#define NT 16               // K-tiles of 128 bytes

typedef int v4i  __attribute__((ext_vector_type(4)));
typedef int v16i __attribute__((ext_vector_type(16)));

__device__ __forceinline__ void gload_lds16(const void* g, void* l) {
    __builtin_amdgcn_global_load_lds(
        (const __attribute__((address_space(1))) void*)g,
        (__attribute__((address_space(3))) void*)l, 16, 0, 0);
}

// ---------------- Kernel 1: smooth-scale + per-token int8 quant ----------------
__global__ __launch_bounds__(256) void quant_kernel(
    const float* __restrict__ x, const float* __restrict__ ss,
    int8_t* __restrict__ xq, float* __restrict__ xscale, int T)
{
    const int wave = threadIdx.x >> 6;
    const int lane = threadIdx.x & 63;
    const int t = blockIdx.x * 4 + wave;
    if (t >= T) return;

    const float4* xrow = (const float4*)(x + (size_t)t * IN_F);
    const float4* ssv  = (const float4*)ss;

    float4 vals[8];
    float amax = 0.f;
#pragma unroll
    for (int it = 0; it < 8; ++it) {
        int idx = it * 64 + lane;
        float4 v = xrow[idx];
        float4 s = ssv[idx];
        v.x *= s.x; v.y *= s.y; v.z *= s.z; v.w *= s.w;
        vals[it] = v;
        amax = fmaxf(amax, fmaxf(fmaxf(fabsf(v.x), fabsf(v.y)),
                                 fmaxf(fabsf(v.z), fabsf(v.w))));
    }
#pragma unroll
    for (int o = 32; o; o >>= 1) amax = fmaxf(amax, __shfl_xor(amax, o, 64));

    float scale = fmaxf(amax * (1.0f / 127.0f), 1e-8f);
    float inv = 1.0f / scale;
    if (lane == 0) xscale[t] = scale;

    int* out = (int*)(xq + (size_t)t * IN_F);
#pragma unroll
    for (int it = 0; it < 8; ++it) {
        float4 v = vals[it];
        int q0 = (int)fminf(fmaxf(rintf(v.x * inv), -128.f), 127.f);
        int q1 = (int)fminf(fmaxf(rintf(v.y * inv), -128.f), 127.f);
        int q2 = (int)fminf(fmaxf(rintf(v.z * inv), -128.f), 127.f);
        int q3 = (int)fminf(fmaxf(rintf(v.w * inv), -128.f), 127.f);
        out[it * 64 + lane] = (q0 & 255) | ((q1 & 255) << 8) |
                              ((q2 & 255) << 16) | ((q3 & 255) << 24);
    }
}

// ---------------- Kernel 2: pack W into MFMA-fragment order ----------------
// Fragment (colblk, kt, ks), lane l holds 16B: col = colblk*32 + (l&31),
// k = kt*128 + ks*32 + (l>>5)*16 + 0..15.
// Byte addr = colblk*65536 + kt*4096 + ks*1024 + l*16.
__global__ __launch_bounds__(256) void pack_wfrag_kernel(
    const int* __restrict__ w, int8_t* __restrict__ w8f)
{
    const int tau = blockIdx.x * 256 + threadIdx.x;   // 0..262143
    const int lane = tau & 63;
    const int rest = tau >> 6;
    const int ks = rest & 3;
    const int kt = (rest >> 2) & 15;
    const int colblk = rest >> 6;
    const int col = colblk * 32 + (lane & 31);
    const int kbase = kt * 128 + ks * 32 + (lane >> 5) * 16;
    const int* src = w + (size_t)col * IN_F + kbase;
    int out[4];
#pragma unroll
    for (int d = 0; d < 4; ++d) {
        int4 v = *(const int4*)(src + d * 4);
        out[d] = (v.x & 255) | ((v.y & 255) << 8) |
                 ((v.z & 255) << 16) | ((v.w & 255) << 24);
    }
    *(int4*)(w8f + (size_t)tau * 16) = *(const int4*)out;
}

// ---------------- Kernel 3: 128x256 i8 GEMM, distance-2 prefetch ----------------
// R15 base + B triple-buffer (distance-2) + 4 A-slots (distance-2). Per tile t:
// issue LOADB(t+2)[8] + STAGE_A(t+2)[4]; COMPUTE(t); vmcnt(12); barrier.
// In-flight never drops below 12 (~2 tiles of latency cover per load).
__global__ __launch_bounds__(256, 2) void gemm_kernel(
    const int8_t* __restrict__ Ag,    // [M, IN_F] quantized activations
    const int8_t* __restrict__ Bf,    // fragment-ordered weights
    const float* __restrict__ xscale,
    const float* __restrict__ wscale,
    const float* __restrict__ bias,
    float* __restrict__ C, int M)
{
    __shared__ __align__(16) int8_t smem[4 * 16384];   // 64 KB: 4 A-slots

    const int tid  = threadIdx.x;
    const int lane = tid & 63;
    const int wc   = tid >> 6;         // wave = N-quarter (0..3), 64 cols each
    const int l31 = lane & 31, hi2 = lane >> 5;
    const int asw = l31 & 7;

    // XCD-bijective swizzle: 1024 blocks, 8 XCDs, 128 per chunk
    const int lb  = blockIdx.x;
    const int swb = (lb & 7) * 128 + (lb >> 3);
    const int bm = swb >> 3;           // 0..127
    const int bn = swb & 7;            // 0..7
    const size_t arow0 = (size_t)bm * BM;

    // A staging: thread covers rows (tid>>3)+32*i, LDS slot (tid&7), pre-swizzled src
    const int st_r = tid >> 3;
    const int st_c = ((tid & 7) ^ ((tid >> 3) & 7)) << 4;

    // A ds_read base: row = m*32 + l31; granule g = ks*2+hi2 at slot col (g^asw)*16
    const int aoff = l31 * 128;

    // B fragment base: wave owns colblks bn*8 + wc*2 {+0,+1} (stride 65536 B)
    const int8_t* bbase = Bf + (size_t)(bn * 8 + wc * 2) * 65536 + lane * 16;

#define STAGE_A(SLOTI, T)                                                        \
    do { _Pragma("unroll") for (int i_ = 0; i_ < 4; ++i_)                        \
        gload_lds16(Ag + (arow0 + i_ * 32 + st_r) * (size_t)IN_F                 \
                        + (size_t)((T) * 128) + st_c,                            \
                    (int8_t*)smem + (SLOTI) * 16384 + i_ * 4096 + tid * 16);     \
    } while (0)

#define LOADB(DST, T)                                                            \
    do { _Pragma("unroll") for (int n_ = 0; n_ < 2; ++n_)                        \
         _Pragma("unroll") for (int k_ = 0; k_ < 4; ++k_)                        \
        DST[n_ * 4 + k_] = *(const v4i*)(bbase + n_ * 65536 + (T) * 4096         \
                                         + k_ * 1024);                           \
    } while (0)

#define RDA(AF, KS)                                                              \
    do { _Pragma("unroll") for (int m_ = 0; m_ < 4; ++m_)                        \
        AF[m_] = *(const v4i*)(sp_ + m_ * 4096 +                                 \
                               ((((KS) * 2 + hi2) ^ asw) << 4));                 \
    } while (0)

#define MFMA8(AF, B, KS)                                                         \
    do { __builtin_amdgcn_s_setprio(1);                                          \
        _Pragma("unroll") for (int m_ = 0; m_ < 4; ++m_)                         \
        _Pragma("unroll") for (int n_ = 0; n_ < 2; ++n_)                         \
            acc[m_][n_] = __builtin_amdgcn_mfma_i32_32x32x32_i8(                 \
                AF[m_], B[n_ * 4 + (KS)], acc[m_][n_], 0, 0, 0);                 \
        __builtin_amdgcn_s_setprio(0); } while (0)

#define COMPUTE(SLOTI, B)                                                        \
    do { const int8_t* sp_ = (const int8_t*)smem + (SLOTI) * 16384 + aoff;       \
        v4i a0_[4], a1_[4];                                                      \
        RDA(a0_, 0);                                                             \
        RDA(a1_, 1); MFMA8(a0_, B, 0);                                           \
        RDA(a0_, 2); MFMA8(a1_, B, 1);                                           \
        RDA(a1_, 3); MFMA8(a0_, B, 2);                                           \
        MFMA8(a1_, B, 3);                                                        \
    } while (0)

// Ledger: per tile t (t<=13) issue LOADB(t+2)[8] then STAGE_A(t+2)[4].
// End-of-t queue: [B(t+1)8, S(t+1)4, B(t+2)8, S(t+2)4]; vmcnt(12) drains
// B(t+1)+S(t+1) (needed at t+1), keeps 12 in flight. t=14: vmcnt(0). t=15: none.
#define TILE(T, BCUR, BNXT)                                                      \
    do {                                                                         \
        if ((T) <= 13) { LOADB(BNXT, (T) + 2); STAGE_A(((T) + 2) & 3, (T) + 2); }\
        COMPUTE((T) & 3, BCUR);                                                  \
        if ((T) <= 13) {                                                         \
            asm volatile("s_waitcnt vmcnt(12)" ::: "memory");                    \
            __builtin_amdgcn_s_barrier();                                        \
        } else if ((T) == 14) {                                                  \
            asm volatile("s_waitcnt vmcnt(0)" ::: "memory");                     \
            __builtin_amdgcn_s_barrier();                                        \
        }                                                                        \
    } while (0)

    v16i acc[4][2] = {};
    v4i B0[8], B1[8], B2[8];

    // prologue: S(0)->slot0, B(0)->B0, S(1)->slot1, B(1)->B1 (24 issues);
    // vmcnt(12) drains S(0)+B(0), leaves S(1)+B(1) in flight.
    STAGE_A(0, 0);
    LOADB(B0, 0);
    STAGE_A(1, 1);
    LOADB(B1, 1);
    asm volatile("s_waitcnt vmcnt(12)" ::: "memory");
    __builtin_amdgcn_s_barrier();

    // use B[t%3], load B(t+2) into B[(t+2)%3]
    TILE(0,  B0, B2); TILE(1,  B1, B0); TILE(2,  B2, B1);
    TILE(3,  B0, B2); TILE(4,  B1, B0); TILE(5,  B2, B1);
    TILE(6,  B0, B2); TILE(7,  B1, B0); TILE(8,  B2, B1);
    TILE(9,  B0, B2); TILE(10, B1, B0); TILE(11, B2, B1);
    TILE(12, B0, B2); TILE(13, B1, B0); TILE(14, B2, B1);
    TILE(15, B0, B1);

    // epilogue: 32x32 C/D layout col = lane&31, row = (reg&3) + 8*(reg>>2) + 4*hi2
    float wsc[2], bs[2];
    int gcol[2];
#pragma unroll
    for (int n = 0; n < 2; ++n) {
        gcol[n] = bn * BN + wc * 64 + n * 32 + l31;
        wsc[n] = wscale[gcol[n]];
        bs[n]  = bias[gcol[n]];
    }
#pragma unroll
    for (int m = 0; m < 4; ++m) {
#pragma unroll
        for (int reg = 0; reg < 16; ++reg) {
            const int row = (reg & 3) + 8 * (reg >> 2) + 4 * hi2;
            const size_t grow = arow0 + m * 32 + row;
            const float xs = xscale[grow];
            float* crow = C + grow * OUT_F;
#pragma unroll
            for (int n = 0; n < 2; ++n)
                __builtin_nontemporal_store(
                    (float)acc[m][n][reg] * xs * wsc[n] + bs[n], crow + gcol[n]);
        }
    }
#undef STAGE_A
#undef LOADB
#undef RDA
#undef MFMA8
#undef COMPUTE
#undef TILE
}

extern "C" void kernel_launch(void* const* d_in, const int* in_sizes, int n_in,
                              void* d_out, int out_size, void* d_ws, size_t ws_size,
                              hipStream_t stream)
{
    const float* x      = (const float*)d_in[0];
    const float* ss     = (const float*)d_in[1];
    const float* wscale = (const float*)d_in[2];
    const float* bias   = (const float*)d_in[3];
    const int*   w32    = (const int*)d_in[4];
    float* out = (float*)d_out;

    const int T = in_sizes[0] / IN_F;   // 16384

    int8_t* xq     = (int8_t*)d_ws;
    float*  xscale = (float*)((char*)d_ws + (size_t)T * IN_F);
    int8_t* w8f    = (int8_t*)((char*)d_ws + (size_t)T * IN_F + (size_t)T * 4);

    quant_kernel<<<dim3((T + 3) / 4), dim3(256), 0, stream>>>(x, ss, xq, xscale, T);
    pack_wfrag_kernel<<<dim3(1024), dim3(256), 0, stream>>>(w32, w8f);
    gemm_kernel<<<dim3((T / BM) * (OUT_F / BN)), dim3(256), 0, stream>>>(
        xq, w8f, xscale, wscale, bias, out, T);
}

// Round 18
// 105.416 us; speedup vs baseline: 1.2590x; 1.2590x over previous
//
#include <hip/hip_runtime.h>
#include <stdint.h>

#define IN_F 2048
#define OUT_F 2048
#define BM 128
#define BN 256
#define NT 16               // K-tiles of 128 bytes

typedef int v4i  __attribute__((ext_vector_type(4)));
typedef int v16i __attribute__((ext_vector_type(16)));

__device__ __forceinline__ void gload_lds16(const void* g, void* l) {
    __builtin_amdgcn_global_load_lds(
        (const __attribute__((address_space(1))) void*)g,
        (__attribute__((address_space(3))) void*)l, 16, 0, 0);
}

// ---------------- Kernel 1: smooth-scale + per-token int8 quant ----------------
__global__ __launch_bounds__(256) void quant_kernel(
    const float* __restrict__ x, const float* __restrict__ ss,
    int8_t* __restrict__ xq, float* __restrict__ xscale, int T)
{
    const int wave = threadIdx.x >> 6;
    const int lane = threadIdx.x & 63;
    const int t = blockIdx.x * 4 + wave;
    if (t >= T) return;

    const float4* xrow = (const float4*)(x + (size_t)t * IN_F);
    const float4* ssv  = (const float4*)ss;

    float4 vals[8];
    float amax = 0.f;
#pragma unroll
    for (int it = 0; it < 8; ++it) {
        int idx = it * 64 + lane;
        float4 v = xrow[idx];
        float4 s = ssv[idx];
        v.x *= s.x; v.y *= s.y; v.z *= s.z; v.w *= s.w;
        vals[it] = v;
        amax = fmaxf(amax, fmaxf(fmaxf(fabsf(v.x), fabsf(v.y)),
                                 fmaxf(fabsf(v.z), fabsf(v.w))));
    }
#pragma unroll
    for (int o = 32; o; o >>= 1) amax = fmaxf(amax, __shfl_xor(amax, o, 64));

    float scale = fmaxf(amax * (1.0f / 127.0f), 1e-8f);
    float inv = 1.0f / scale;
    if (lane == 0) xscale[t] = scale;

    int* out = (int*)(xq + (size_t)t * IN_F);
#pragma unroll
    for (int it = 0; it < 8; ++it) {
        float4 v = vals[it];
        int q0 = (int)fminf(fmaxf(rintf(v.x * inv), -128.f), 127.f);
        int q1 = (int)fminf(fmaxf(rintf(v.y * inv), -128.f), 127.f);
        int q2 = (int)fminf(fmaxf(rintf(v.z * inv), -128.f), 127.f);
        int q3 = (int)fminf(fmaxf(rintf(v.w * inv), -128.f), 127.f);
        out[it * 64 + lane] = (q0 & 255) | ((q1 & 255) << 8) |
                              ((q2 & 255) << 16) | ((q3 & 255) << 24);
    }
}

// ---------------- Kernel 2: pack W into MFMA-fragment order ----------------
// Fragment (colblk, kt, ks), lane l holds 16B: col = colblk*32 + (l&31),
// k = kt*128 + ks*32 + (l>>5)*16 + 0..15.
// Byte addr = colblk*65536 + kt*4096 + ks*1024 + l*16.
__global__ __launch_bounds__(256) void pack_wfrag_kernel(
    const int* __restrict__ w, int8_t* __restrict__ w8f)
{
    const int tau = blockIdx.x * 256 + threadIdx.x;   // 0..262143
    const int lane = tau & 63;
    const int rest = tau >> 6;
    const int ks = rest & 3;
    const int kt = (rest >> 2) & 15;
    const int colblk = rest >> 6;
    const int col = colblk * 32 + (lane & 31);
    const int kbase = kt * 128 + ks * 32 + (lane >> 5) * 16;
    const int* src = w + (size_t)col * IN_F + kbase;
    int out[4];
#pragma unroll
    for (int d = 0; d < 4; ++d) {
        int4 v = *(const int4*)(src + d * 4);
        out[d] = (v.x & 255) | ((v.y & 255) << 8) |
                 ((v.z & 255) << 16) | ((v.w & 255) << 24);
    }
    *(int4*)(w8f + (size_t)tau * 16) = *(const int4*)out;
}

// ---------------- Kernel 3: 128x256 i8 GEMM, 4 waves (1Mx4N), 2 blocks/CU ----------
// Wave tile 128x64: m_rep=4, n_rep=2 -> each A ds_read feeds 2 MFMAs.
// A in LDS 3-deep (16KB slots, shared by all 4 waves); B fragment-direct from L2,
// distance-1 prefetch, 2 reg buffers. Per tile t: LOADB(t+1), STAGE_A(t+2),
// COMPUTE(t), vmcnt(4), barrier.
__global__ __launch_bounds__(256, 2) void gemm_kernel(
    const int8_t* __restrict__ Ag,    // [M, IN_F] quantized activations
    const int8_t* __restrict__ Bf,    // fragment-ordered weights
    const float* __restrict__ xscale,
    const float* __restrict__ wscale,
    const float* __restrict__ bias,
    float* __restrict__ C, int M)
{
    __shared__ __align__(16) int8_t smem[3 * 16384];   // 48 KB: 3 A-slots

    const int tid  = threadIdx.x;
    const int lane = tid & 63;
    const int wc   = tid >> 6;         // wave = N-quarter (0..3), 64 cols each
    const int l31 = lane & 31, hi2 = lane >> 5;
    const int asw = l31 & 7;

    // XCD-bijective swizzle: 1024 blocks, 8 XCDs, 128 per chunk
    const int lb  = blockIdx.x;
    const int swb = (lb & 7) * 128 + (lb >> 3);
    const int bm = swb >> 3;           // 0..127
    const int bn = swb & 7;            // 0..7
    const size_t arow0 = (size_t)bm * BM;

    // A staging: thread covers rows (tid>>3)+32*i, LDS slot (tid&7), pre-swizzled src
    const int st_r = tid >> 3;
    const int st_c = ((tid & 7) ^ ((tid >> 3) & 7)) << 4;

    // A ds_read base: row = m*32 + l31; granule g = ks*2+hi2 at slot col (g^asw)*16
    const int aoff = l31 * 128;

    // B fragment base: wave owns colblks bn*8 + wc*2 {+0,+1} (stride 65536 B)
    const int8_t* bbase = Bf + (size_t)(bn * 8 + wc * 2) * 65536 + lane * 16;

#define STAGE_A(SLOTI, T)                                                        \
    do { _Pragma("unroll") for (int i_ = 0; i_ < 4; ++i_)                        \
        gload_lds16(Ag + (arow0 + i_ * 32 + st_r) * (size_t)IN_F                 \
                        + (size_t)((T) * 128) + st_c,                            \
                    (int8_t*)smem + (SLOTI) * 16384 + i_ * 4096 + tid * 16);     \
    } while (0)

#define LOADB(DST, T)                                                            \
    do { _Pragma("unroll") for (int n_ = 0; n_ < 2; ++n_)                        \
         _Pragma("unroll") for (int k_ = 0; k_ < 4; ++k_)                        \
        DST[n_ * 4 + k_] = *(const v4i*)(bbase + n_ * 65536 + (T) * 4096         \
                                         + k_ * 1024);                           \
    } while (0)

#define RDA(AF, KS)                                                              \
    do { _Pragma("unroll") for (int m_ = 0; m_ < 4; ++m_)                        \
        AF[m_] = *(const v4i*)(sp_ + m_ * 4096 +                                 \
                               ((((KS) * 2 + hi2) ^ asw) << 4));                 \
    } while (0)

#define MFMA8(AF, B, KS)                                                         \
    do { __builtin_amdgcn_s_setprio(1);                                          \
        _Pragma("unroll") for (int m_ = 0; m_ < 4; ++m_)                         \
        _Pragma("unroll") for (int n_ = 0; n_ < 2; ++n_)                         \
            acc[m_][n_] = __builtin_amdgcn_mfma_i32_32x32x32_i8(                 \
                AF[m_], B[n_ * 4 + (KS)], acc[m_][n_], 0, 0, 0);                 \
        __builtin_amdgcn_s_setprio(0); } while (0)

#define COMPUTE(SLOTI, B)                                                        \
    do { const int8_t* sp_ = (const int8_t*)smem + (SLOTI) * 16384 + aoff;       \
        v4i a0_[4], a1_[4];                                                      \
        RDA(a0_, 0);                                                             \
        RDA(a1_, 1); MFMA8(a0_, B, 0);                                           \
        RDA(a0_, 2); MFMA8(a1_, B, 1);                                           \
        RDA(a1_, 3); MFMA8(a0_, B, 2);                                           \
        MFMA8(a1_, B, 3);                                                        \
    } while (0)

// Per-tile ledger (audited): issue LOADB(t+1)[8] then STAGE(t+2)[4].
// Steady outstanding at end = S(t+1)[4], B(t+1)[8], S(t+2)[4]; vmcnt(4)
// drains S(t+1)+B(t+1), leaves S(t+2) in flight. Never 0 until t=14.
#define TILE(T, BCUR, BNXT)                                                      \
    do {                                                                         \
        if ((T) <= 14) LOADB(BNXT, (T) + 1);                                     \
        if ((T) <= 13) STAGE_A(((T) + 2) % 3, (T) + 2);                          \
        COMPUTE((T) % 3, BCUR);                                                  \
        if ((T) <= 13) {                                                         \
            asm volatile("s_waitcnt vmcnt(4)" ::: "memory");                     \
            __builtin_amdgcn_s_barrier();                                        \
        } else if ((T) == 14) {                                                  \
            asm volatile("s_waitcnt vmcnt(0)" ::: "memory");                     \
            __builtin_amdgcn_s_barrier();                                        \
        }                                                                        \
    } while (0)

    v16i acc[4][2] = {};
    v4i B0[8], B1[8];

    // prologue: S(0)->slot0, B(0)->B0, S(1)->slot1; vmcnt(4) leaves S(1) in flight
    STAGE_A(0, 0);
    LOADB(B0, 0);
    STAGE_A(1, 1);
    asm volatile("s_waitcnt vmcnt(4)" ::: "memory");
    __builtin_amdgcn_s_barrier();

#pragma unroll
    for (int t = 0; t < NT; t += 2) {
        TILE(t, B0, B1);
        TILE(t + 1, B1, B0);
    }

    // epilogue: 32x32 C/D layout col = lane&31, row = (reg&3) + 8*(reg>>2) + 4*hi2
    float wsc[2], bs[2];
    int gcol[2];
#pragma unroll
    for (int n = 0; n < 2; ++n) {
        gcol[n] = bn * BN + wc * 64 + n * 32 + l31;
        wsc[n] = wscale[gcol[n]];
        bs[n]  = bias[gcol[n]];
    }
#pragma unroll
    for (int m = 0; m < 4; ++m) {
#pragma unroll
        for (int reg = 0; reg < 16; ++reg) {
            const int row = (reg & 3) + 8 * (reg >> 2) + 4 * hi2;
            const size_t grow = arow0 + m * 32 + row;
            const float xs = xscale[grow];
            float* crow = C + grow * OUT_F;
#pragma unroll
            for (int n = 0; n < 2; ++n)
                __builtin_nontemporal_store(
                    (float)acc[m][n][reg] * xs * wsc[n] + bs[n], crow + gcol[n]);
        }
    }
#undef STAGE_A
#undef LOADB
#undef RDA
#undef MFMA8
#undef COMPUTE
#undef TILE
}

extern "C" void kernel_launch(void* const* d_in, const int* in_sizes, int n_in,
                              void* d_out, int out_size, void* d_ws, size_t ws_size,
                              hipStream_t stream)
{
    const float* x      = (const float*)d_in[0];
    const float* ss     = (const float*)d_in[1];
    const float* wscale = (const float*)d_in[2];
    const float* bias   = (const float*)d_in[3];
    const int*   w32    = (const int*)d_in[4];
    float* out = (float*)d_out;

    const int T = in_sizes[0] / IN_F;   // 16384

    int8_t* xq     = (int8_t*)d_ws;
    float*  xscale = (float*)((char*)d_ws + (size_t)T * IN_F);
    int8_t* w8f    = (int8_t*)((char*)d_ws + (size_t)T * IN_F + (size_t)T * 4);

    quant_kernel<<<dim3((T + 3) / 4), dim3(256), 0, stream>>>(x, ss, xq, xscale, T);
    pack_wfrag_kernel<<<dim3(1024), dim3(256), 0, stream>>>(w32, w8f);
    gemm_kernel<<<dim3((T / BM) * (OUT_F / BN)), dim3(256), 0, stream>>>(
        xq, w8f, xscale, wscale, bias, out, T);
}